// Round 8
// baseline (617.447 us; speedup 1.0000x reference)
//
#include <hip/hip_runtime.h>

#define TT 1024
#define LOG2E 1.4426950408889634f
#define LN2   0.6931471805599453f

typedef __attribute__((ext_vector_type(4))) float f32x4;
typedef __attribute__((ext_vector_type(2))) _Float16 half2_t;
typedef __attribute__((ext_vector_type(4))) _Float16 half4;

#if __has_builtin(__builtin_amdgcn_exp2f)
#define EXP2F(x) __builtin_amdgcn_exp2f(x)
#else
#define EXP2F(x) exp2f(x)
#endif
#if __has_builtin(__builtin_amdgcn_logf)
#define LOG2F(x) __builtin_amdgcn_logf(x)
#else
#define LOG2F(x) log2f(x)
#endif
#define RCPF(x) __builtin_amdgcn_rcpf(x)

// Gates computed TRANSPOSED via v_mfma_f32_16x16x16f16 (D layout == B layout:
// updated h feeds the next step's B fragment directly — no LDS in recurrence).
// Gate domain pre-scaled into exp2 space (i,f,o: -log2e; g: +2log2e; cell kept
// as Cs = 2*log2e*c) with merged reciprocals: 5 exp2 + 2 rcp per element — the
// algebraic floor for an exp-based LSTM cell.
//
// Round-8: r5/r7 counter fit shows busy cycles are identical with or without
// packed-asm (mov overhead = pk savings) and ~20-25% of elapsed is dependency
// stall. This version is PURE SCALAR (no ext-vector math, no inline asm) with
// four explicitly independent row chains and all 16 gate exps grouped up
// front, maximizing schedulable ILP around the quarter-rate trans pipe.
__global__ __launch_bounds__(256, 2)
void lstm_head_kernel(const float* __restrict__ x,
                      const float* __restrict__ W_ih,
                      const float* __restrict__ W_hh,
                      const float* __restrict__ b_ih,
                      const float* __restrict__ b_hh,
                      const float* __restrict__ W1,
                      const float* __restrict__ b1,
                      const float* __restrict__ W2,
                      const float* __restrict__ b2,
                      float* __restrict__ out)
{
    __shared__ float lds_f[4][16 * 17];   // final h fp32 staging for the head

    const int tid  = threadIdx.x;
    const int wib  = tid >> 6;
    const int lane = tid & 63;
    const int n    = lane & 15;           // batch within tile (and A-row m)
    const int q    = lane >> 4;           // quadrant
    const int batch0 = (blockIdx.x * 4 + wib) * 16;

    const float KG = 2.0f * LOG2E;        // g-gate / cell-domain scale

    // ---- fixed per-lane constants (pre-scaled into exp2 domain) ----
    half4 wfrag[4];        // A fragments: scaled W_hh rows g*16 + n, k = q*4+i
    float wih[4][4];       // scaled W_ih at D rows q*4+r
    float bias[4][4];      // scaled (b_ih + b_hh)
    #pragma unroll
    for (int g = 0; g < 4; ++g) {
        const float sc = (g == 2) ? KG : -LOG2E;   // i,f,o -> -log2e; g -> +2log2e
        const int arow = g * 16 + n;               // A: m = lane&15
        half4 wf;
        #pragma unroll
        for (int i = 0; i < 4; ++i)
            wf[i] = (_Float16)(W_hh[arow * 16 + (q * 4 + i)] * sc);
        wfrag[g] = wf;
        #pragma unroll
        for (int r = 0; r < 4; ++r) {
            const int row = g * 16 + q * 4 + r;    // D: row = q*4+r
            wih[g][r]  = W_ih[row] * sc;
            bias[g][r] = (b_ih[row] + b_hh[row]) * sc;
        }
    }

    half4 hfrag = {(_Float16)0.f, (_Float16)0.f, (_Float16)0.f, (_Float16)0.f};
    float Cs[4]   = {0.f, 0.f, 0.f, 0.f};   // scaled cell state
    float hreg[4] = {0.f, 0.f, 0.f, 0.f};   // last h (fp32)

    const float* xp = x + (size_t)(batch0 + n) * TT;   // quads read same addr (broadcast)

    for (int t4 = 0; t4 < TT; t4 += 4) {
        const float4 xv = *(const float4*)(xp + t4);
        const float xs4[4] = {xv.x, xv.y, xv.z, xv.w};

        #pragma unroll
        for (int s = 0; s < 4; ++s) {
            const float xs = xs4[s];

            // ---- gate MFMAs (C-init carries x*W_ih + bias, fp32) ----
            f32x4 acc[4];
            #pragma unroll
            for (int g = 0; g < 4; ++g) {
                f32x4 ci;
                #pragma unroll
                for (int r = 0; r < 4; ++r)
                    ci[r] = fmaf(wih[g][r], xs, bias[g][r]);
                acc[g] = __builtin_amdgcn_mfma_f32_16x16x16f16(wfrag[g], hfrag, ci, 0, 0, 0);
            }

            // ---- all 16 gate exps grouped (dependency-free trans burst) ----
            float e[4][4];
            #pragma unroll
            for (int g = 0; g < 4; ++g)
                #pragma unroll
                for (int r = 0; r < 4; ++r)
                    e[g][r] = EXP2F(acc[g][r]);

            // ---- four independent scalar row chains ----
            #pragma unroll
            for (int r = 0; r < 4; ++r) {
                const float ei = e[0][r];   // e^{-ai}
                const float ef = e[1][r];   // e^{-af}
                const float eg = e[2][r];   // e^{2ag}
                const float eo = e[3][r];   // e^{-ao}
                // c' = c/(1+ef) + (eg-1)/((1+ei)(eg+1))  [scaled by KG]
                const float pei = ei + 1.0f;
                const float pef = ef + 1.0f;
                const float egp = eg + 1.0f;
                const float egm = fmaf(KG, eg, -KG);      // KG*(eg-1)
                const float P   = pei * egp;
                const float D   = pef * P;
                const float t2  = pef * egm;
                const float num = fmaf(Cs[r], P, t2);
                const float Cn  = num * RCPF(D);
                Cs[r] = Cn;
                // h = (ec-1)/((1+eo)(ec+1)),  ec = exp2(Cn)
                const float ec  = EXP2F(Cn);
                const float peo = eo + 1.0f;
                const float ecp = ec + 1.0f;
                const float ecm = ec - 1.0f;
                const float D2  = peo * ecp;
                hreg[r] = ecm * RCPF(D2);
            }

            // ---- h back to f16 B-fragment (2x packed cvt) ----
            const half2_t lo = __builtin_bit_cast(half2_t,
                                  __builtin_amdgcn_cvt_pkrtz(hreg[0], hreg[1]));
            const half2_t hi = __builtin_bit_cast(half2_t,
                                  __builtin_amdgcn_cvt_pkrtz(hreg[2], hreg[3]));
            hfrag = (half4){lo.x, lo.y, hi.x, hi.y};
        }
    }

    // ---- head: stage final h (fp32) -> 16 lanes do MLP + log_softmax ----
    float* fh = lds_f[wib];
    #pragma unroll
    for (int r = 0; r < 4; ++r)
        fh[n * 17 + (q * 4 + r)] = hreg[r];   // fh[batch][hid]

    if (lane < 16) {
        const int b = batch0 + lane;
        float hvv[16];
        #pragma unroll
        for (int j = 0; j < 16; ++j) hvv[j] = fh[lane * 17 + j];

        float a1[32];
        #pragma unroll
        for (int u = 0; u < 32; ++u) {
            float s = b1[u];
            #pragma unroll
            for (int j = 0; j < 16; ++j) s = fmaf(W1[u * 16 + j], hvv[j], s);
            a1[u] = fmaxf(s, 0.0f);
        }

        float z[6];
        float m = -1e30f;
        #pragma unroll
        for (int v = 0; v < 6; ++v) {
            float s = b2[v];
            #pragma unroll
            for (int u = 0; u < 32; ++u) s = fmaf(W2[v * 32 + u], a1[u], s);
            z[v] = s;
            m = fmaxf(m, s);
        }
        float se = 0.0f;
        #pragma unroll
        for (int v = 0; v < 6; ++v) se += EXP2F((z[v] - m) * LOG2E);
        const float lse = m + LOG2F(se) * LN2;
        #pragma unroll
        for (int v = 0; v < 6; ++v) out[b * 6 + v] = z[v] - lse;
    }
}

extern "C" void kernel_launch(void* const* d_in, const int* in_sizes, int n_in,
                              void* d_out, int out_size, void* d_ws, size_t ws_size,
                              hipStream_t stream) {
    const float* x    = (const float*)d_in[0];
    const float* W_ih = (const float*)d_in[1];
    const float* W_hh = (const float*)d_in[2];
    const float* b_ih = (const float*)d_in[3];
    const float* b_hh = (const float*)d_in[4];
    const float* W1   = (const float*)d_in[5];
    const float* b1   = (const float*)d_in[6];
    const float* W2   = (const float*)d_in[7];
    const float* b2   = (const float*)d_in[8];
    float* out = (float*)d_out;

    const int B = out_size / 6;          // 32768
    const int nblocks = B / 64;          // 64 batch per block (4 waves x 16)

    hipLaunchKernelGGL(lstm_head_kernel, dim3(nblocks), dim3(256), 0, stream,
                       x, W_ih, W_hh, b_ih, b_hh, W1, b1, W2, b2, out);
}